// Round 1
// baseline (142.620 us; speedup 1.0000x reference)
//
#include <hip/hip_runtime.h>
#include <hip/hip_bf16.h>

// Eq4Net: permutation-equivariant 4th-order set network.
// Exploits: (a) layer-1 input T = x^{⊗4} is rank-1 per channel -> all 15
// marginals are closed-form in S_d = sum_i x[b,i,d]; (b) only pooled output
// needed -> layer-2 marginal terms pre-contracted with coefs2 into small
// lookup tables. T1 (post-relu layer-1) materialized once in bf16 (42MB).

#define NB 4
#define NN 24
#define ND 16
#define NS 16
#define NO 16
#define NKL 576
#define TILE 9216  // NKL*NS

typedef unsigned int u32;
typedef unsigned short u16;

__device__ __forceinline__ u16 f2bf(float f) {
  u32 u = __float_as_uint(f);
  u = (u + 0x7fffu + ((u >> 16) & 1u)) >> 16;  // RNE
  return (u16)u;
}

// ---------------- K0: x = [relu(embed[xcat]) , xfeat], S = sum_i x ----------
__global__ __launch_bounds__(256) void k0_prep(
    const int* __restrict__ xcat, const float* __restrict__ xfeat,
    const float* __restrict__ embed, const float* __restrict__ b_out,
    float* __restrict__ xw, float* __restrict__ Sw, float* __restrict__ out) {
  __shared__ float sx[NB * NN * ND];
  const int t = threadIdx.x;
  for (int idx = t; idx < NB * NN * ND; idx += 256) {
    int d = idx & (ND - 1);
    int bi = idx >> 4;  // b*NN+i
    float v;
    if (d < 15) v = fmaxf(embed[xcat[bi] * 15 + d], 0.0f);
    else        v = xfeat[bi];
    sx[idx] = v;
    xw[idx] = v;
  }
  __syncthreads();
  for (int idx = t; idx < NB * ND; idx += 256) {
    int d = idx & (ND - 1), b = idx >> 4;
    float s = 0.0f;
    for (int i = 0; i < NN; ++i) s += sx[(b * NN + i) * ND + d];
    Sw[idx] = s;
  }
  if (t < NB) out[t] = b_out[0];
}

// ---------------- K2: layer 1 + relu -> T1 (bf16) + m_k, m_l ----------------
// block = (b,i,j); per element (k,l):
//   pre[s] = sum_d alpha[d,s]*x_k[d]*x_l[d] + Bt[k][s] + Gt[l][s] + dconst[s]
__global__ __launch_bounds__(192) void k2_layer1(
    const float* __restrict__ xw, const float* __restrict__ Sw,
    const float* __restrict__ coefs1, const float* __restrict__ bias1,
    u16* __restrict__ T1, float* __restrict__ m_k, float* __restrict__ m_l) {
  const int blk = blockIdx.x;
  const int j = blk % NN, i = (blk / NN) % NN, b = blk / (NN * NN);
  const int t = threadIdx.x;
  __shared__ __align__(16) float sx[NN * ND];
  __shared__ __align__(16) float alphaT[NS][ND];
  __shared__ float tb[ND][NS], tg[ND][NS], td[ND][NS];
  __shared__ float Bt[NN][20], Gt[NN][20];  // pitch 20: bank-spread, 16B-align
  __shared__ float dconst[NS];
  __shared__ float T1s[NKL][17];            // f32 tile for marginal reduction

  const float* xb = xw + b * NN * ND;
  for (int idx = t; idx < NN * ND; idx += 192) sx[idx] = xb[idx];
  __syncthreads();

  // per-(d,s) basis combination tables
  for (int idx = t; idx < ND * NS; idx += 192) {
    int d = idx >> 4, s = idx & 15;
    const float* c = coefs1 + (d * NS + s) * 16;
    float xi = sx[i * ND + d], xj = sx[j * ND + d];
    float Sv = Sw[b * ND + d];
    float S2 = Sv * Sv, S3 = S2 * Sv, S4 = S2 * S2;
    float pij = xi * xj;
    // coeff of x_k*x_l (bases 0,1,2,5); of x_k (4,7,9,12); of x_l (3,6,8,11);
    // constant (10,13,14,15)
    alphaT[s][d] = c[0] * pij + c[1] * Sv * xj + c[2] * Sv * xi + c[5] * S2;
    tb[d][s] = c[4] * Sv * pij + c[9] * S2 * xi + c[7] * S2 * xj + c[12] * S3;
    tg[d][s] = c[3] * Sv * pij + c[8] * S2 * xi + c[6] * S2 * xj + c[11] * S3;
    td[d][s] = c[10] * S2 * pij + c[14] * S3 * xi + c[13] * S3 * xj + c[15] * S4;
  }
  __syncthreads();
  for (int idx = t; idx < NN * NS; idx += 192) {
    int k = idx >> 4, s = idx & 15;
    float sb = 0.f, sg = 0.f;
    for (int d = 0; d < ND; ++d) {
      float xv = sx[k * ND + d];
      sb += tb[d][s] * xv;
      sg += tg[d][s] * xv;
    }
    Bt[k][s] = sb;
    Gt[k][s] = sg;
  }
  if (t < NS) {
    float sd = 0.f;
    for (int d = 0; d < ND; ++d) sd += td[d][t];
    dconst[t] = sd + bias1[t];
  }
  __syncthreads();

  const int kl0 = t, kl1 = t + 192, kl2 = t + 384;  // 3*192 = 576 exact
  const int k0 = kl0 / NN, l0 = kl0 % NN;
  const int k1 = kl1 / NN, l1 = kl1 % NN;
  const int k2_ = kl2 / NN, l2 = kl2 % NN;

  float P0[ND], P1[ND], P2[ND];
#pragma unroll
  for (int d = 0; d < ND; ++d) {
    P0[d] = sx[k0 * ND + d] * sx[l0 * ND + d];
    P1[d] = sx[k1 * ND + d] * sx[l1 * ND + d];
    P2[d] = sx[k2_ * ND + d] * sx[l2 * ND + d];
  }
  float A0[NS], A1[NS], A2[NS];
#pragma unroll
  for (int s = 0; s < NS; ++s) {
    A0[s] = dconst[s] + Bt[k0][s] + Gt[l0][s];
    A1[s] = dconst[s] + Bt[k1][s] + Gt[l1][s];
    A2[s] = dconst[s] + Bt[k2_][s] + Gt[l2][s];
  }
#pragma unroll
  for (int s = 0; s < NS; ++s) {
    float a0 = A0[s], a1 = A1[s], a2 = A2[s];
#pragma unroll
    for (int d = 0; d < ND; ++d) {
      float av = alphaT[s][d];
      a0 += av * P0[d];
      a1 += av * P1[d];
      a2 += av * P2[d];
    }
    A0[s] = a0; A1[s] = a1; A2[s] = a2;
  }

  auto store_elem = [&](float (&A)[NS], int kl) {
    u32 w[8];
#pragma unroll
    for (int m = 0; m < 8; ++m) {
      float v0 = fmaxf(A[2 * m], 0.f);
      float v1 = fmaxf(A[2 * m + 1], 0.f);
      T1s[kl][2 * m] = v0;
      T1s[kl][2 * m + 1] = v1;
      w[m] = (u32)f2bf(v0) | ((u32)f2bf(v1) << 16);
    }
    uint4* gp = (uint4*)(T1 + (size_t)blk * TILE + (size_t)kl * NS);
    gp[0] = make_uint4(w[0], w[1], w[2], w[3]);
    gp[1] = make_uint4(w[4], w[5], w[6], w[7]);
  };
  store_elem(A0, kl0);
  store_elem(A1, kl1);
  store_elem(A2, kl2);
  __syncthreads();

  // m_k[b][i][j][l][s] = sum_k T1 ; m_l[b][i][j][k][s] = sum_l T1  (block-unique)
  float* mk = m_k + (size_t)((b * NN + i) * NN + j) * NN * NS;
  float* ml = m_l + (size_t)((b * NN + i) * NN + j) * NN * NS;
  for (int idx = t; idx < NN * NS; idx += 192) {
    int a = idx >> 4, s = idx & 15;
    float sk = 0.f, sl = 0.f;
    for (int c = 0; c < NN; ++c) {
      sk += T1s[c * NN + a][s];   // a = l, sum over k
      sl += T1s[a * NN + c][s];   // a = k, sum over l
    }
    mk[idx] = sk;
    ml[idx] = sl;
  }
}

// ---------------- K3: m_i (sum over i) and m_j (sum over j) from T1 ---------
__global__ __launch_bounds__(256) void k3_margins(
    const u16* __restrict__ T1, float* __restrict__ m_i, float* __restrict__ m_j) {
  const int blkid = blockIdx.x, t = threadIdx.x;
  if (blkid < NB * NN) {
    const int b = blkid / NN, i = blkid % NN;
    const u16* base = T1 + (size_t)((b * NN + i) * NN) * TILE;
    float* outp = m_j + (size_t)(b * NN + i) * TILE;  // m_j keeps (i,k,l)
    for (int pe = t; pe < TILE / 2; pe += 256) {
      float s0 = 0.f, s1 = 0.f;
      for (int jj = 0; jj < NN; ++jj) {
        u32 u = *(const u32*)(base + (size_t)jj * TILE + 2 * pe);
        s0 += __uint_as_float(u << 16);
        s1 += __uint_as_float(u & 0xffff0000u);
      }
      float2 r; r.x = s0; r.y = s1;
      ((float2*)outp)[pe] = r;
    }
  } else {
    const int id2 = blkid - NB * NN;
    const int b = id2 / NN, jj = id2 % NN;
    const u16* base = T1 + (size_t)(b * NN * NN + jj) * TILE;
    float* outp = m_i + (size_t)(b * NN + jj) * TILE;  // m_i keeps (j,k,l)
    for (int pe = t; pe < TILE / 2; pe += 256) {
      float s0 = 0.f, s1 = 0.f;
      for (int ii = 0; ii < NN; ++ii) {
        u32 u = *(const u32*)(base + (size_t)ii * NN * TILE + 2 * pe);
        s0 += __uint_as_float(u << 16);
        s1 += __uint_as_float(u & 0xffff0000u);
      }
      float2 r; r.x = s0; r.y = s1;
      ((float2*)outp)[pe] = r;
    }
  }
}

// ---------------- K4a1: pair marginals from single-axis marginals -----------
__global__ __launch_bounds__(256) void k4a1(
    const float* __restrict__ mi, const float* __restrict__ mj, const float* __restrict__ mk,
    float* __restrict__ mij, float* __restrict__ mik, float* __restrict__ mil,
    float* __restrict__ mjk, float* __restrict__ mjl, float* __restrict__ mkl) {
  int id = blockIdx.x * 256 + threadIdx.x;
  const int SZ = NB * NN * NN * NS;  // 36864 (= NB*NKL*NS)
  if (id < SZ) {  // mij[b][kl][s] = sum_j mi[b][j][kl][s]
    int s = id & 15, kl = (id >> 4) % NKL, b = id / (NS * NKL);
    const float* p = mi + ((size_t)b * NN * NKL + kl) * NS + s;
    float a = 0.f;
    for (int x = 0; x < NN; ++x) a += p[(size_t)x * NKL * NS];
    mij[id] = a; return;
  }
  id -= SZ;
  if (id < SZ) {  // mik[b][j][l][s] = sum_k mi[b][j][k*NN+l][s]
    int s = id & 15, r = id >> 4; int l = r % NN; r /= NN; int jj = r % NN; int b = r / NN;
    const float* p = mi + (((size_t)b * NN + jj) * NKL + l) * NS + s;
    float a = 0.f;
    for (int x = 0; x < NN; ++x) a += p[x * NN * NS];
    mik[id] = a; return;
  }
  id -= SZ;
  if (id < SZ) {  // mil[b][j][k][s] = sum_l mi[b][j][k*NN+l][s]
    int s = id & 15, r = id >> 4; int k = r % NN; r /= NN; int jj = r % NN; int b = r / NN;
    const float* p = mi + (((size_t)b * NN + jj) * NKL + k * NN) * NS + s;
    float a = 0.f;
    for (int x = 0; x < NN; ++x) a += p[x * NS];
    mil[id] = a; return;
  }
  id -= SZ;
  if (id < SZ) {  // mjk[b][i][l][s] = sum_k mj[b][i][k*NN+l][s]
    int s = id & 15, r = id >> 4; int l = r % NN; r /= NN; int ii = r % NN; int b = r / NN;
    const float* p = mj + (((size_t)b * NN + ii) * NKL + l) * NS + s;
    float a = 0.f;
    for (int x = 0; x < NN; ++x) a += p[x * NN * NS];
    mjk[id] = a; return;
  }
  id -= SZ;
  if (id < SZ) {  // mjl[b][i][k][s] = sum_l mj[b][i][k*NN+l][s]
    int s = id & 15, r = id >> 4; int k = r % NN; r /= NN; int ii = r % NN; int b = r / NN;
    const float* p = mj + (((size_t)b * NN + ii) * NKL + k * NN) * NS + s;
    float a = 0.f;
    for (int x = 0; x < NN; ++x) a += p[x * NS];
    mjl[id] = a; return;
  }
  id -= SZ;
  if (id < SZ) {  // mkl[b][i][j][s] = sum_l mk[b][i][j][l][s]
    int s = id & 15, r = id >> 4; int jj = r % NN; r /= NN; int ii = r % NN; int b = r / NN;
    const float* p = mk + ((size_t)((b * NN + ii) * NN + jj) * NN) * NS + s;
    float a = 0.f;
    for (int x = 0; x < NN; ++x) a += p[x * NS];
    mkl[id] = a; return;
  }
}

// ---------------- K4a2: triple marginals from pair marginals ----------------
__global__ __launch_bounds__(256) void k4a2(
    const float* __restrict__ mij, const float* __restrict__ mik, const float* __restrict__ mjk,
    float* __restrict__ mijk, float* __restrict__ mijl,
    float* __restrict__ mikl, float* __restrict__ mjkl) {
  int id = blockIdx.x * 256 + threadIdx.x;
  const int SZ = NB * NN * NS;  // 1536
  if (id < SZ) {  // mijk[b][l][s] = sum_k mij[b][k*NN+l][s]
    int s = id & 15, r = id >> 4; int l = r % NN; int b = r / NN;
    const float* p = mij + ((size_t)b * NKL + l) * NS + s;
    float a = 0.f;
    for (int x = 0; x < NN; ++x) a += p[x * NN * NS];
    mijk[id] = a; return;
  }
  id -= SZ;
  if (id < SZ) {  // mijl[b][k][s] = sum_l mij[b][k*NN+l][s]
    int s = id & 15, r = id >> 4; int k = r % NN; int b = r / NN;
    const float* p = mij + ((size_t)b * NKL + k * NN) * NS + s;
    float a = 0.f;
    for (int x = 0; x < NN; ++x) a += p[x * NS];
    mijl[id] = a; return;
  }
  id -= SZ;
  if (id < SZ) {  // mikl[b][j][s] = sum_l mik[b][j][l][s]
    int s = id & 15, r = id >> 4; int jj = r % NN; int b = r / NN;
    const float* p = mik + ((size_t)(b * NN + jj) * NN) * NS + s;
    float a = 0.f;
    for (int x = 0; x < NN; ++x) a += p[x * NS];
    mikl[id] = a; return;
  }
  id -= SZ;
  if (id < SZ) {  // mjkl[b][i][s] = sum_l mjk[b][i][l][s]
    int s = id & 15, r = id >> 4; int ii = r % NN; int b = r / NN;
    const float* p = mjk + ((size_t)(b * NN + ii) * NN) * NS + s;
    float a = 0.f;
    for (int x = 0; x < NN; ++x) a += p[x * NS];
    mjkl[id] = a; return;
  }
}

// ---------------- K4a3: quad marginal from triple ---------------------------
__global__ __launch_bounds__(64) void k4a3(
    const float* __restrict__ mijk, float* __restrict__ mijkl) {
  int id = threadIdx.x;  // 64 = NB*NS
  int s = id & 15, b = id >> 4;
  const float* p = mijk + (size_t)b * NN * NS + s;
  float a = 0.f;
  for (int x = 0; x < NN; ++x) a += p[x * NS];
  mijkl[id] = a;
}

// ---------------- K4b: in-place contract marginals with coefs2 --------------
// out16[s2] = sum_s coefs2[s][s2][basis] * in16[s]
__global__ __launch_bounds__(256) void k4b(
    float* __restrict__ mi, float* __restrict__ mj, float* __restrict__ mk,
    float* __restrict__ ml, float* __restrict__ mij, float* __restrict__ mik,
    float* __restrict__ mil, float* __restrict__ mjk, float* __restrict__ mjl,
    float* __restrict__ mkl, float* __restrict__ mijk, float* __restrict__ mijl,
    float* __restrict__ mikl, float* __restrict__ mjkl, float* __restrict__ mijkl,
    const float* __restrict__ coefs2) {
  __shared__ float c2[NS * NO * 16];
  for (int idx = threadIdx.x; idx < NS * NO * 16; idx += 256) c2[idx] = coefs2[idx];
  __syncthreads();
  int pos = blockIdx.x * 256 + threadIdx.x;
  const int PBIG = NB * NN * NKL;  // 55296
  const int PMED = NB * NN * NN;   // 2304
  const int PSM = NB * NN;         // 96
  float* ptr; int basis;
  if (pos < PBIG) { ptr = mi + (size_t)pos * NS; basis = 1; }
  else if ((pos -= PBIG) < PBIG) { ptr = mj + (size_t)pos * NS; basis = 2; }
  else if ((pos -= PBIG) < PBIG) { ptr = mk + (size_t)pos * NS; basis = 3; }
  else if ((pos -= PBIG) < PBIG) { ptr = ml + (size_t)pos * NS; basis = 4; }
  else if ((pos -= PBIG) < PMED) { ptr = mij + (size_t)pos * NS; basis = 5; }
  else if ((pos -= PMED) < PMED) { ptr = mik + (size_t)pos * NS; basis = 6; }
  else if ((pos -= PMED) < PMED) { ptr = mil + (size_t)pos * NS; basis = 7; }
  else if ((pos -= PMED) < PMED) { ptr = mjk + (size_t)pos * NS; basis = 8; }
  else if ((pos -= PMED) < PMED) { ptr = mjl + (size_t)pos * NS; basis = 9; }
  else if ((pos -= PMED) < PMED) { ptr = mkl + (size_t)pos * NS; basis = 10; }
  else if ((pos -= PMED) < PSM) { ptr = mijk + (size_t)pos * NS; basis = 11; }
  else if ((pos -= PSM) < PSM) { ptr = mijl + (size_t)pos * NS; basis = 12; }
  else if ((pos -= PSM) < PSM) { ptr = mikl + (size_t)pos * NS; basis = 13; }
  else if ((pos -= PSM) < PSM) { ptr = mjkl + (size_t)pos * NS; basis = 14; }
  else if ((pos -= PSM) < NB) { ptr = mijkl + (size_t)pos * NS; basis = 15; }
  else return;
  float in[NS];
#pragma unroll
  for (int s = 0; s < NS; ++s) in[s] = ptr[s];
  float outv[NO];
#pragma unroll
  for (int s2 = 0; s2 < NO; ++s2) {
    float a = 0.f;
#pragma unroll
    for (int s = 0; s < NS; ++s) a += c2[(s * NO + s2) * 16 + basis] * in[s];
    outv[s2] = a;
  }
#pragma unroll
  for (int s2 = 0; s2 < NO; ++s2) ptr[s2] = outv[s2];
}

// ---------------- K5: layer 2 + relu + pool + w_out -------------------------
__global__ __launch_bounds__(192) void k5_layer2(
    const u16* __restrict__ T1,
    const float* __restrict__ mi, const float* __restrict__ mj,
    const float* __restrict__ mk, const float* __restrict__ ml,
    const float* __restrict__ mij, const float* __restrict__ mik,
    const float* __restrict__ mil, const float* __restrict__ mjk,
    const float* __restrict__ mjl, const float* __restrict__ mkl,
    const float* __restrict__ mijk, const float* __restrict__ mijl,
    const float* __restrict__ mikl, const float* __restrict__ mjkl,
    const float* __restrict__ mijkl,
    const float* __restrict__ coefs2, const float* __restrict__ bias2,
    const float* __restrict__ w_out, float* __restrict__ out) {
  const int blk = blockIdx.x;
  const int j = blk % NN, i = (blk / NN) % NN, b = blk / (NN * NN);
  const int t = threadIdx.x;
  __shared__ __align__(16) float c2id[NS][NO];
  __shared__ float Kt[NN][20], Lt[NN][20];
  __shared__ float cterm[NO], wl[NO];
  __shared__ float wsum[3];

  for (int idx = t; idx < NS * NO; idx += 192)
    c2id[idx >> 4][idx & 15] = coefs2[idx * 16];  // basis 0
  for (int idx = t; idx < NN * NO; idx += 192) {
    int k = idx >> 4, s2 = idx & 15;
    Kt[k][s2] = ml[(size_t)(((b * NN + i) * NN + j) * NN + k) * NS + s2]
              + mjl[(size_t)((b * NN + i) * NN + k) * NS + s2]
              + mil[(size_t)((b * NN + j) * NN + k) * NS + s2]
              + mijl[(size_t)(b * NN + k) * NS + s2];
    Lt[k][s2] = mk[(size_t)(((b * NN + i) * NN + j) * NN + k) * NS + s2]
              + mjk[(size_t)((b * NN + i) * NN + k) * NS + s2]
              + mik[(size_t)((b * NN + j) * NN + k) * NS + s2]
              + mijk[(size_t)(b * NN + k) * NS + s2];
  }
  if (t < NO) {
    cterm[t] = mkl[(size_t)((b * NN + i) * NN + j) * NS + t]
             + mikl[(size_t)(b * NN + j) * NS + t]
             + mjkl[(size_t)(b * NN + i) * NS + t]
             + mijkl[(size_t)b * NS + t] + bias2[t];
    wl[t] = w_out[t];
  }
  __syncthreads();

  const int kl0 = t, kl1 = t + 192, kl2 = t + 384;
  const int k0 = kl0 / NN, l0 = kl0 % NN;
  const int k1 = kl1 / NN, l1 = kl1 % NN;
  const int k2_ = kl2 / NN, l2 = kl2 % NN;

  float acc0[NO], acc1[NO], acc2[NO];
#pragma unroll
  for (int s2 = 0; s2 < NO; ++s2) {
    acc0[s2] = cterm[s2] + Kt[k0][s2] + Lt[l0][s2];
    acc1[s2] = cterm[s2] + Kt[k1][s2] + Lt[l1][s2];
    acc2[s2] = cterm[s2] + Kt[k2_][s2] + Lt[l2][s2];
  }
  // big lookup terms (already contracted with coefs2)
  {
    const float* p10 = mi + ((size_t)(b * NN + j) * NKL + kl0) * NS;
    const float* p20 = mj + ((size_t)(b * NN + i) * NKL + kl0) * NS;
    const float* p50 = mij + ((size_t)b * NKL + kl0) * NS;
    const float* p11 = mi + ((size_t)(b * NN + j) * NKL + kl1) * NS;
    const float* p21 = mj + ((size_t)(b * NN + i) * NKL + kl1) * NS;
    const float* p51 = mij + ((size_t)b * NKL + kl1) * NS;
    const float* p12 = mi + ((size_t)(b * NN + j) * NKL + kl2) * NS;
    const float* p22 = mj + ((size_t)(b * NN + i) * NKL + kl2) * NS;
    const float* p52 = mij + ((size_t)b * NKL + kl2) * NS;
#pragma unroll
    for (int s2 = 0; s2 < NO; ++s2) {
      acc0[s2] += p10[s2] + p20[s2] + p50[s2];
      acc1[s2] += p11[s2] + p21[s2] + p51[s2];
      acc2[s2] += p12[s2] + p22[s2] + p52[s2];
    }
  }
  // identity term: sum_s c2id[s][s2] * T1[s]
  const u16* tp = T1 + (size_t)blk * TILE;
  u32 pk0[8], pk1[8], pk2[8];
  {
    uint4 q0 = ((const uint4*)(tp + (size_t)kl0 * NS))[0];
    uint4 q1 = ((const uint4*)(tp + (size_t)kl0 * NS))[1];
    pk0[0]=q0.x; pk0[1]=q0.y; pk0[2]=q0.z; pk0[3]=q0.w;
    pk0[4]=q1.x; pk0[5]=q1.y; pk0[6]=q1.z; pk0[7]=q1.w;
    q0 = ((const uint4*)(tp + (size_t)kl1 * NS))[0];
    q1 = ((const uint4*)(tp + (size_t)kl1 * NS))[1];
    pk1[0]=q0.x; pk1[1]=q0.y; pk1[2]=q0.z; pk1[3]=q0.w;
    pk1[4]=q1.x; pk1[5]=q1.y; pk1[6]=q1.z; pk1[7]=q1.w;
    q0 = ((const uint4*)(tp + (size_t)kl2 * NS))[0];
    q1 = ((const uint4*)(tp + (size_t)kl2 * NS))[1];
    pk2[0]=q0.x; pk2[1]=q0.y; pk2[2]=q0.z; pk2[3]=q0.w;
    pk2[4]=q1.x; pk2[5]=q1.y; pk2[6]=q1.z; pk2[7]=q1.w;
  }
#pragma unroll
  for (int m = 0; m < 8; ++m) {
    float lo0 = __uint_as_float(pk0[m] << 16), hi0 = __uint_as_float(pk0[m] & 0xffff0000u);
    float lo1 = __uint_as_float(pk1[m] << 16), hi1 = __uint_as_float(pk1[m] & 0xffff0000u);
    float lo2 = __uint_as_float(pk2[m] << 16), hi2 = __uint_as_float(pk2[m] & 0xffff0000u);
#pragma unroll
    for (int s2 = 0; s2 < NO; ++s2) {
      float ca = c2id[2 * m][s2], cb = c2id[2 * m + 1][s2];
      acc0[s2] += ca * lo0 + cb * hi0;
      acc1[s2] += ca * lo1 + cb * hi1;
      acc2[s2] += ca * lo2 + cb * hi2;
    }
  }
  float p = 0.f;
#pragma unroll
  for (int s2 = 0; s2 < NO; ++s2)
    p += wl[s2] * (fmaxf(acc0[s2], 0.f) + fmaxf(acc1[s2], 0.f) + fmaxf(acc2[s2], 0.f));
  // wave reduce (64 lanes) then cross-wave via LDS
  for (int off = 32; off > 0; off >>= 1) p += __shfl_down(p, off, 64);
  if ((t & 63) == 0) wsum[t >> 6] = p;
  __syncthreads();
  if (t == 0) atomicAdd(&out[b], wsum[0] + wsum[1] + wsum[2]);
}

// ---------------- launch -----------------------------------------------------
extern "C" void kernel_launch(void* const* d_in, const int* in_sizes, int n_in,
                              void* d_out, int out_size, void* d_ws, size_t ws_size,
                              hipStream_t stream) {
  (void)in_sizes; (void)n_in; (void)out_size; (void)ws_size;
  const int*   xcat   = (const int*)d_in[0];
  const float* xfeat  = (const float*)d_in[1];
  const float* embed  = (const float*)d_in[2];
  const float* coefs1 = (const float*)d_in[3];
  const float* bias1  = (const float*)d_in[4];
  const float* coefs2 = (const float*)d_in[5];
  const float* bias2  = (const float*)d_in[6];
  const float* w_out  = (const float*)d_in[7];
  const float* b_out  = (const float*)d_in[8];
  float* out = (float*)d_out;
  char* ws = (char*)d_ws;

  float* xw   = (float*)(ws + 0);          // 6144 B
  float* Sw   = (float*)(ws + 6144);       // 256 B
  u16*   T1   = (u16*)(ws + 8192);         // 2304*9216*2 = 42467328 B
  float* m_i  = (float*)(ws + 42475520);   // 3538944 B each
  float* m_j  = (float*)(ws + 46014464);
  float* m_k  = (float*)(ws + 49553408);
  float* m_l  = (float*)(ws + 53092352);
  float* mij  = (float*)(ws + 56631296);   // 147456 B each
  float* mik  = (float*)(ws + 56778752);
  float* mil  = (float*)(ws + 56926208);
  float* mjk  = (float*)(ws + 57073664);
  float* mjl  = (float*)(ws + 57221120);
  float* mkl  = (float*)(ws + 57368576);
  float* mijk = (float*)(ws + 57516032);   // 6144 B each
  float* mijl = (float*)(ws + 57522176);
  float* mikl = (float*)(ws + 57528320);
  float* mjkl = (float*)(ws + 57534464);
  float* mijkl= (float*)(ws + 57540608);   // 256 B

  k0_prep<<<1, 256, 0, stream>>>(xcat, xfeat, embed, b_out, xw, Sw, out);
  k2_layer1<<<NB * NN * NN, 192, 0, stream>>>(xw, Sw, coefs1, bias1, T1, m_k, m_l);
  k3_margins<<<2 * NB * NN, 256, 0, stream>>>(T1, m_i, m_j);
  k4a1<<<(6 * NB * NN * NN * NS + 255) / 256, 256, 0, stream>>>(
      m_i, m_j, m_k, mij, mik, mil, mjk, mjl, mkl);
  k4a2<<<(4 * NB * NN * NS + 255) / 256, 256, 0, stream>>>(
      mij, mik, mjk, mijk, mijl, mikl, mjkl);
  k4a3<<<1, 64, 0, stream>>>(mijk, mijkl);
  k4b<<<(4 * 55296 + 6 * 2304 + 4 * 96 + 4 + 255) / 256, 256, 0, stream>>>(
      m_i, m_j, m_k, m_l, mij, mik, mil, mjk, mjl, mkl,
      mijk, mijl, mikl, mjkl, mijkl, coefs2);
  k5_layer2<<<NB * NN * NN, 192, 0, stream>>>(
      T1, m_i, m_j, m_k, m_l, mij, mik, mil, mjk, mjl, mkl,
      mijk, mijl, mikl, mjkl, mijkl, coefs2, bias2, w_out, out);
}